// Round 1
// baseline (665.668 us; speedup 1.0000x reference)
//
#include <hip/hip_runtime.h>
#include <math.h>

#define H        2048
#define HD       12288      // (NG+1)*H
#define DICT     50000
#define FDIM     6
#define RDIM     1
#define IN_DIM   16
#define EPS_F    1e-8f

// d_out flat offsets (floats), in reference return order
#define OFF_PI   ((size_t)0)
#define OFF_V    ((size_t)8)
#define OFF_H    ((size_t)9)
#define OFF_C    ((size_t)2057)
#define OFF_FK   ((size_t)4105)
#define OFF_FV   ((size_t)304105)
#define OFF_RK   ((size_t)102704105)
#define OFF_RV   ((size_t)102754105)

struct F4U { float x, y, z, w; };   // 4-byte-aligned float4 (d_out sections are odd-float offset)

__device__ __forceinline__ float sigf(float v) { return 1.0f / (1.0f + expf(-v)); }

// ---------------- zero scratch accumulators ----------------
__global__ void k_zero(float* __restrict__ p, int n) {
    int i = blockIdx.x * 256 + threadIdx.x;
    if (i < n) p[i] = 0.0f;
}

// ---------------- preact[r] = W_i2h[r,:]@x + W_h2h[r,:]@h + b  (wave per row) ----------------
__global__ __launch_bounds__(256) void k_preact(
    const float* __restrict__ W_h2h, const float* __restrict__ W_i2h,
    const float* __restrict__ b_h2h, const float* __restrict__ b_i2h,
    const float* __restrict__ h, const float* __restrict__ x,
    float* __restrict__ preact)
{
    int gid  = blockIdx.x * blockDim.x + threadIdx.x;
    int row  = gid >> 6;
    int lane = threadIdx.x & 63;
    if (row >= HD) return;
    const float4* Wv = (const float4*)(W_h2h + (size_t)row * H);
    const float4* hv = (const float4*)h;
    float acc = 0.0f;
#pragma unroll
    for (int k = 0; k < 8; ++k) {
        float4 w4 = Wv[lane + (k << 6)];
        float4 h4 = hv[lane + (k << 6)];
        acc += w4.x * h4.x + w4.y * h4.y + w4.z * h4.z + w4.w * h4.w;
    }
    if (lane < IN_DIM) acc += W_i2h[(size_t)row * IN_DIM + lane] * x[lane];
#pragma unroll
    for (int off = 32; off > 0; off >>= 1) acc += __shfl_down(acc, off);
    if (lane == 0) preact[row] = acc + b_h2h[row] + b_i2h[row];
}

// ---------------- DND softmax weights (one block) + keys copy ----------------
__global__ __launch_bounds__(1024) void k_dnd_weights(
    const float* __restrict__ keys, const float* __restrict__ x,
    float* __restrict__ w, float* __restrict__ keys_out,
    int dim, int xoff)
{
    __shared__ float red[16];
    __shared__ float gbuf;
    const int tid = threadIdx.x;

    float qn[6]; float qs = 0.0f;
    for (int d = 0; d < dim; ++d) { float q = x[xoff + d]; qn[d] = q; qs += q * q; }
    float qi = 1.0f / (sqrtf(qs) + EPS_F);
    for (int d = 0; d < dim; ++d) qn[d] *= qi;

    float lmax = -__builtin_inff();
    for (int i = tid; i < DICT; i += 1024) {
        float ks = 0.0f, dot = 0.0f;
        for (int d = 0; d < dim; ++d) {
            float kv = keys[(size_t)i * dim + d];
            keys_out[(size_t)i * dim + d] = kv;   // fused output copy
            ks += kv * kv; dot += kv * qn[d];
        }
        float sim = dot / (sqrtf(ks) + EPS_F);
        w[i] = sim;
        lmax = fmaxf(lmax, sim);
    }
#pragma unroll
    for (int off = 32; off > 0; off >>= 1) lmax = fmaxf(lmax, __shfl_down(lmax, off));
    if ((tid & 63) == 0) red[tid >> 6] = lmax;
    __syncthreads();
    if (tid == 0) { float m = red[0]; for (int i = 1; i < 16; ++i) m = fmaxf(m, red[i]); gbuf = m; }
    __syncthreads();
    const float gmax = gbuf;
    __syncthreads();

    float lsum = 0.0f;
    for (int i = tid; i < DICT; i += 1024) {
        float e = expf(w[i] - gmax);
        w[i] = e; lsum += e;
    }
#pragma unroll
    for (int off = 32; off > 0; off >>= 1) lsum += __shfl_down(lsum, off);
    if ((tid & 63) == 0) red[tid >> 6] = lsum;
    __syncthreads();
    if (tid == 0) { float s = 0.0f; for (int i = 0; i < 16; ++i) s += red[i]; gbuf = 1.0f / s; }
    __syncthreads();
    const float ginv = gbuf;
    for (int i = tid; i < DICT; i += 1024) w[i] *= ginv;
}

// ---------------- fused vals copy + weighted sum ----------------
// grid: (chunks=400, stripes=2, dict=2); block 256. Each thread owns one float4 column.
#define ROWS_PER_CHUNK 125
__global__ __launch_bounds__(256) void k_copy_wsum(
    const float* __restrict__ f_vals, const float* __restrict__ r_vals,
    const float* __restrict__ wf, const float* __restrict__ wr,
    float* __restrict__ out_fv, float* __restrict__ out_rv,
    float* __restrict__ memfun, float* __restrict__ memrul)
{
    __shared__ float wl[ROWS_PER_CHUNK];
    const int tid    = threadIdx.x;
    const int chunk  = blockIdx.x;
    const int stripe = blockIdx.y;
    const int dict   = blockIdx.z;

    const float* vals = dict ? r_vals : f_vals;
    const float* w    = dict ? wr     : wf;
    float*       outv = dict ? out_rv : out_fv;
    float*       mem  = dict ? memrul : memfun;

    const int row0 = chunk * ROWS_PER_CHUNK;
    if (tid < ROWS_PER_CHUNK) wl[tid] = w[row0 + tid];
    __syncthreads();

    const int colf = stripe * 256 + tid;            // float4 column, 0..511
    const float4* vv = (const float4*)vals;
    F4U*          ov = (F4U*)outv;

    float ax = 0.f, ay = 0.f, az = 0.f, aw = 0.f;
    size_t base = (size_t)row0 * 512 + colf;
#pragma unroll 5
    for (int i = 0; i < ROWS_PER_CHUNK; ++i) {
        float4 v = vv[base];
        F4U s; s.x = v.x; s.y = v.y; s.z = v.z; s.w = v.w;
        ov[base] = s;
        float wv = wl[i];
        ax += wv * v.x; ay += wv * v.y; az += wv * v.z; aw += wv * v.w;
        base += 512;
    }
    const int c = colf * 4;
    atomicAdd(&mem[c + 0], ax);
    atomicAdd(&mem[c + 1], ay);
    atomicAdd(&mem[c + 2], az);
    atomicAdd(&mem[c + 3], aw);
}

// ---------------- gates -> c_t, h_t; write h/c outputs + write_idx rows ----------------
__global__ __launch_bounds__(256) void k_combine(
    const float* __restrict__ preact, const float* __restrict__ c_in,
    const float* __restrict__ memfun, const float* __restrict__ memrul,
    const float* __restrict__ x, const int* __restrict__ widx_p,
    float* __restrict__ out, float* __restrict__ ht_ws)
{
    const int j = blockIdx.x * 256 + threadIdx.x;
    if (j >= H) return;
    const int widx = *widx_p;

    float f_t   = sigf(preact[0 * H + j]);
    float i_t   = sigf(preact[1 * H + j]);
    float o_t   = sigf(preact[2 * H + j]);
    float fun_t = sigf(preact[3 * H + j]);
    float rul_t = sigf(preact[4 * H + j]);
    float c_new = tanhf(preact[5 * H + j]);

    float ct = f_t * c_in[j] + i_t * c_new
             + fun_t * tanhf(memfun[j]) + rul_t * tanhf(memrul[j]);
    float ht = o_t * tanhf(ct);

    out[OFF_H + j] = ht;
    out[OFF_C + j] = ct;
    ht_ws[j] = ht;

    out[OFF_FV + (size_t)widx * H + j] = (j < H / 2) ? ct : 0.0f;
    out[OFF_RV + (size_t)widx * H + j] = (j < H / 2) ? 0.0f : ct;
    if (j < FDIM)  out[OFF_FK + (size_t)widx * FDIM + j] = x[j];
    if (j == FDIM) out[OFF_RK + (size_t)widx] = x[FDIM];
}

// ---------------- ha = relu(W_ih @ h_t + b_ih)  (wave per row) ----------------
__global__ __launch_bounds__(256) void k_hidden(
    const float* __restrict__ W_ih, const float* __restrict__ b_ih,
    const float* __restrict__ ht, float* __restrict__ ha)
{
    int gid  = blockIdx.x * blockDim.x + threadIdx.x;
    int row  = gid >> 6;
    int lane = threadIdx.x & 63;
    if (row >= H) return;
    const float4* Wv = (const float4*)(W_ih + (size_t)row * H);
    const float4* hv = (const float4*)ht;
    float acc = 0.0f;
#pragma unroll
    for (int k = 0; k < 8; ++k) {
        float4 w4 = Wv[lane + (k << 6)];
        float4 h4 = hv[lane + (k << 6)];
        acc += w4.x * h4.x + w4.y * h4.y + w4.z * h4.z + w4.w * h4.w;
    }
#pragma unroll
    for (int off = 32; off > 0; off >>= 1) acc += __shfl_down(acc, off);
    if (lane == 0) ha[row] = fmaxf(acc + b_ih[row], 0.0f);
}

// ---------------- actor softmax + critic ----------------
__global__ __launch_bounds__(256) void k_heads(
    const float* __restrict__ W_actor, const float* __restrict__ b_actor,
    const float* __restrict__ W_critic, const float* __restrict__ b_critic,
    const float* __restrict__ ha, float* __restrict__ out)
{
    __shared__ float red[4];
    __shared__ float logits[9];
    const int tid = threadIdx.x;

    for (int o = 0; o < 9; ++o) {
        const float* row = (o < 8) ? (W_actor + (size_t)o * H) : W_critic;
        float acc = 0.0f;
        for (int k = tid; k < H; k += 256) acc += row[k] * ha[k];
#pragma unroll
        for (int off = 32; off > 0; off >>= 1) acc += __shfl_down(acc, off);
        if ((tid & 63) == 0) red[tid >> 6] = acc;
        __syncthreads();
        if (tid == 0)
            logits[o] = red[0] + red[1] + red[2] + red[3] + ((o < 8) ? b_actor[o] : b_critic[0]);
        __syncthreads();
    }
    if (tid == 0) {
        float m = logits[0];
        for (int o = 1; o < 8; ++o) m = fmaxf(m, logits[o]);
        float e[8], s = 0.0f;
        for (int o = 0; o < 8; ++o) { e[o] = expf(logits[o] - m); s += e[o]; }
        for (int o = 0; o < 8; ++o) out[OFF_PI + o] = e[o] / s;
        out[OFF_V] = logits[8];
    }
}

extern "C" void kernel_launch(void* const* d_in, const int* in_sizes, int n_in,
                              void* d_out, int out_size, void* d_ws, size_t ws_size,
                              hipStream_t stream)
{
    const float* x        = (const float*)d_in[0];
    const float* h        = (const float*)d_in[1];
    const float* c        = (const float*)d_in[2];
    const float* W_i2h    = (const float*)d_in[3];
    const float* b_i2h    = (const float*)d_in[4];
    const float* W_h2h    = (const float*)d_in[5];
    const float* b_h2h    = (const float*)d_in[6];
    const float* f_keys   = (const float*)d_in[7];
    const float* f_vals   = (const float*)d_in[8];
    const float* r_keys   = (const float*)d_in[9];
    const float* r_vals   = (const float*)d_in[10];
    const float* W_ih     = (const float*)d_in[11];
    const float* b_ih     = (const float*)d_in[12];
    const float* W_actor  = (const float*)d_in[13];
    const float* b_actor  = (const float*)d_in[14];
    const float* W_critic = (const float*)d_in[15];
    const float* b_critic = (const float*)d_in[16];
    const int*   widx     = (const int*)d_in[17];

    float* out = (float*)d_out;
    float* ws  = (float*)d_ws;

    // ws layout (floats)
    float* preact = ws;                 // 12288
    float* wf     = ws + 12288;         // 50000
    float* wr     = ws + 62288;         // 50000
    float* memfun = ws + 112288;        // 2048
    float* memrul = ws + 114336;        // 2048  (contiguous with memfun)
    float* ht_ws  = ws + 116384;        // 2048
    float* ha     = ws + 118432;        // 2048

    // 1. zero accumulators (ws is poisoned, and atomics accumulate)
    k_zero<<<16, 256, 0, stream>>>(memfun, 2 * H);

    // 2. LSTM preact GEMV
    k_preact<<<HD / 4, 256, 0, stream>>>(W_h2h, W_i2h, b_h2h, b_i2h, h, x, preact);

    // 3./4. DND softmax weights (+ keys output copies)
    k_dnd_weights<<<1, 1024, 0, stream>>>(f_keys, x, wf, out + OFF_FK, FDIM, 0);
    k_dnd_weights<<<1, 1024, 0, stream>>>(r_keys, x, wr, out + OFF_RK, RDIM, FDIM);

    // 5. fused vals copy + weighted sums (dominant kernel)
    k_copy_wsum<<<dim3(DICT / ROWS_PER_CHUNK, 2, 2), 256, 0, stream>>>(
        f_vals, r_vals, wf, wr, out + OFF_FV, out + OFF_RV, memfun, memrul);

    // 6. gates -> c_t, h_t; h/c outputs + write_idx rows
    k_combine<<<H / 256, 256, 0, stream>>>(preact, c, memfun, memrul, x, widx, out, ht_ws);

    // 7. heads
    k_hidden<<<H / 4, 256, 0, stream>>>(W_ih, b_ih, ht_ws, ha);
    k_heads<<<1, 256, 0, stream>>>(W_actor, b_actor, W_critic, b_critic, ha, out);
}

// Round 2
// 461.194 us; speedup vs baseline: 1.4434x; 1.4434x over previous
//
#include <hip/hip_runtime.h>
#include <math.h>

#define H        2048
#define HD       12288      // (NG+1)*H
#define DICT     50000
#define FDIM     6
#define RDIM     1
#define IN_DIM   16
#define EPS_F    1e-8f

// d_out flat offsets (floats), in reference return order
#define OFF_PI   ((size_t)0)
#define OFF_V    ((size_t)8)
#define OFF_H    ((size_t)9)
#define OFF_C    ((size_t)2057)
#define OFF_FK   ((size_t)4105)
#define OFF_FV   ((size_t)304105)
#define OFF_RK   ((size_t)102704105)
#define OFF_RV   ((size_t)102754105)

struct F4U { float x, y, z, w; };   // 4-byte-aligned float4 (d_out vals sections are odd-float offset)

__device__ __forceinline__ float sigf(float v) { return 1.0f / (1.0f + expf(-v)); }

// ---------------- zero scratch accumulators ----------------
__global__ void k_zero(float* __restrict__ p, int n) {
    int i = blockIdx.x * 256 + threadIdx.x;
    if (i < n) p[i] = 0.0f;
}

// ---------------- preact[r] = W_i2h[r,:]@x + W_h2h[r,:]@h + b  (wave per row) ----------------
__global__ __launch_bounds__(256) void k_preact(
    const float* __restrict__ W_h2h, const float* __restrict__ W_i2h,
    const float* __restrict__ b_h2h, const float* __restrict__ b_i2h,
    const float* __restrict__ h, const float* __restrict__ x,
    float* __restrict__ preact)
{
    int gid  = blockIdx.x * blockDim.x + threadIdx.x;
    int row  = gid >> 6;
    int lane = threadIdx.x & 63;
    if (row >= HD) return;
    const float4* Wv = (const float4*)(W_h2h + (size_t)row * H);
    const float4* hv = (const float4*)h;
    float acc = 0.0f;
#pragma unroll
    for (int k = 0; k < 8; ++k) {
        float4 w4 = Wv[lane + (k << 6)];
        float4 h4 = hv[lane + (k << 6)];
        acc += w4.x * h4.x + w4.y * h4.y + w4.z * h4.z + w4.w * h4.w;
    }
    if (lane < IN_DIM) acc += W_i2h[(size_t)row * IN_DIM + lane] * x[lane];
#pragma unroll
    for (int off = 32; off > 0; off >>= 1) acc += __shfl_down(acc, off);
    if (lane == 0) preact[row] = acc + b_h2h[row] + b_i2h[row];
}

// ---------------- grid-wide DND: e_i = exp(cos_sim_i), keys copy, atomic sum ----------------
// Softmax max-subtraction is unnecessary: cosine sim is in [-1,1], exp is in [e^-1, e].
// Normalization (1/sum) is applied later in k_combine.
__global__ __launch_bounds__(256) void k_sims(
    const float* __restrict__ f_keys, const float* __restrict__ r_keys,
    const float* __restrict__ x,
    float* __restrict__ ef, float* __restrict__ er,
    float* __restrict__ sums,              // sums[0]=f, sums[1]=r (pre-zeroed)
    float* __restrict__ out_fk, float* __restrict__ out_rk)
{
    __shared__ float red[4];
    const int i    = blockIdx.x * 256 + threadIdx.x;
    const int dict = blockIdx.y;
    float e = 0.0f;

    if (dict == 0) {
        float qn[FDIM]; float qs = 0.0f;
        for (int d = 0; d < FDIM; ++d) { float q = x[d]; qn[d] = q; qs += q * q; }
        float qi = 1.0f / (sqrtf(qs) + EPS_F);
        if (i < DICT) {
            float ks = 0.0f, dot = 0.0f;
            for (int d = 0; d < FDIM; ++d) {
                float kv = f_keys[(size_t)i * FDIM + d];
                out_fk[(size_t)i * FDIM + d] = kv;       // fused keys output copy
                ks += kv * kv; dot += kv * qn[d];
            }
            float sim = (dot * qi) / (sqrtf(ks) + EPS_F);
            e = expf(sim);
            ef[i] = e;
        }
    } else {
        float q  = x[FDIM];
        float qn = q / (fabsf(q) + EPS_F);
        if (i < DICT) {
            float kv = r_keys[i];
            out_rk[i] = kv;                              // fused keys output copy
            float sim = (kv * qn) / (fabsf(kv) + EPS_F);
            e = expf(sim);
            er[i] = e;
        }
    }
#pragma unroll
    for (int off = 32; off > 0; off >>= 1) e += __shfl_down(e, off);
    if ((threadIdx.x & 63) == 0) red[threadIdx.x >> 6] = e;
    __syncthreads();
    if (threadIdx.x == 0)
        atomicAdd(&sums[dict], red[0] + red[1] + red[2] + red[3]);
}

// ---------------- fused vals copy + (unnormalized) weighted sum ----------------
// grid: (chunks=400, stripes=2, dict=2); block 256. Each thread owns one float4 column.
#define ROWS_PER_CHUNK 125
__global__ __launch_bounds__(256) void k_copy_wsum(
    const float* __restrict__ f_vals, const float* __restrict__ r_vals,
    const float* __restrict__ wf, const float* __restrict__ wr,
    float* __restrict__ out_fv, float* __restrict__ out_rv,
    float* __restrict__ memfun, float* __restrict__ memrul)
{
    __shared__ float wl[ROWS_PER_CHUNK];
    const int tid    = threadIdx.x;
    const int chunk  = blockIdx.x;
    const int stripe = blockIdx.y;
    const int dict   = blockIdx.z;

    const float* vals = dict ? r_vals : f_vals;
    const float* w    = dict ? wr     : wf;
    float*       outv = dict ? out_rv : out_fv;
    float*       mem  = dict ? memrul : memfun;

    const int row0 = chunk * ROWS_PER_CHUNK;
    if (tid < ROWS_PER_CHUNK) wl[tid] = w[row0 + tid];
    __syncthreads();

    const int colf = stripe * 256 + tid;            // float4 column, 0..511
    const float4* vv = (const float4*)vals;
    F4U*          ov = (F4U*)outv;

    float ax = 0.f, ay = 0.f, az = 0.f, aw = 0.f;
    size_t base = (size_t)row0 * 512 + colf;
#pragma unroll 5
    for (int i = 0; i < ROWS_PER_CHUNK; ++i) {
        float4 v = vv[base];
        F4U s; s.x = v.x; s.y = v.y; s.z = v.z; s.w = v.w;
        ov[base] = s;
        float wv = wl[i];
        ax += wv * v.x; ay += wv * v.y; az += wv * v.z; aw += wv * v.w;
        base += 512;
    }
    const int c = colf * 4;
    atomicAdd(&mem[c + 0], ax);
    atomicAdd(&mem[c + 1], ay);
    atomicAdd(&mem[c + 2], az);
    atomicAdd(&mem[c + 3], aw);
}

// ---------------- gates -> c_t, h_t; write h/c outputs + write_idx rows ----------------
__global__ __launch_bounds__(256) void k_combine(
    const float* __restrict__ preact, const float* __restrict__ c_in,
    const float* __restrict__ memfun, const float* __restrict__ memrul,
    const float* __restrict__ sums,
    const float* __restrict__ x, const int* __restrict__ widx_p,
    float* __restrict__ out, float* __restrict__ ht_ws)
{
    const int j = blockIdx.x * 256 + threadIdx.x;
    if (j >= H) return;
    const int widx = *widx_p;
    const float invf = 1.0f / sums[0];
    const float invr = 1.0f / sums[1];

    float f_t   = sigf(preact[0 * H + j]);
    float i_t   = sigf(preact[1 * H + j]);
    float o_t   = sigf(preact[2 * H + j]);
    float fun_t = sigf(preact[3 * H + j]);
    float rul_t = sigf(preact[4 * H + j]);
    float c_new = tanhf(preact[5 * H + j]);

    float ct = f_t * c_in[j] + i_t * c_new
             + fun_t * tanhf(memfun[j] * invf) + rul_t * tanhf(memrul[j] * invr);
    float ht = o_t * tanhf(ct);

    out[OFF_H + j] = ht;
    out[OFF_C + j] = ct;
    ht_ws[j] = ht;

    out[OFF_FV + (size_t)widx * H + j] = (j < H / 2) ? ct : 0.0f;
    out[OFF_RV + (size_t)widx * H + j] = (j < H / 2) ? 0.0f : ct;
    if (j < FDIM)  out[OFF_FK + (size_t)widx * FDIM + j] = x[j];
    if (j == FDIM) out[OFF_RK + (size_t)widx] = x[FDIM];
}

// ---------------- ha = relu(W_ih @ h_t + b_ih)  (wave per row) ----------------
__global__ __launch_bounds__(256) void k_hidden(
    const float* __restrict__ W_ih, const float* __restrict__ b_ih,
    const float* __restrict__ ht, float* __restrict__ ha)
{
    int gid  = blockIdx.x * blockDim.x + threadIdx.x;
    int row  = gid >> 6;
    int lane = threadIdx.x & 63;
    if (row >= H) return;
    const float4* Wv = (const float4*)(W_ih + (size_t)row * H);
    const float4* hv = (const float4*)ht;
    float acc = 0.0f;
#pragma unroll
    for (int k = 0; k < 8; ++k) {
        float4 w4 = Wv[lane + (k << 6)];
        float4 h4 = hv[lane + (k << 6)];
        acc += w4.x * h4.x + w4.y * h4.y + w4.z * h4.z + w4.w * h4.w;
    }
#pragma unroll
    for (int off = 32; off > 0; off >>= 1) acc += __shfl_down(acc, off);
    if (lane == 0) ha[row] = fmaxf(acc + b_ih[row], 0.0f);
}

// ---------------- actor softmax + critic ----------------
__global__ __launch_bounds__(256) void k_heads(
    const float* __restrict__ W_actor, const float* __restrict__ b_actor,
    const float* __restrict__ W_critic, const float* __restrict__ b_critic,
    const float* __restrict__ ha, float* __restrict__ out)
{
    __shared__ float red[4];
    __shared__ float logits[9];
    const int tid = threadIdx.x;

    for (int o = 0; o < 9; ++o) {
        const float* row = (o < 8) ? (W_actor + (size_t)o * H) : W_critic;
        float acc = 0.0f;
        for (int k = tid; k < H; k += 256) acc += row[k] * ha[k];
#pragma unroll
        for (int off = 32; off > 0; off >>= 1) acc += __shfl_down(acc, off);
        if ((tid & 63) == 0) red[tid >> 6] = acc;
        __syncthreads();
        if (tid == 0)
            logits[o] = red[0] + red[1] + red[2] + red[3] + ((o < 8) ? b_actor[o] : b_critic[0]);
        __syncthreads();
    }
    if (tid == 0) {
        float m = logits[0];
        for (int o = 1; o < 8; ++o) m = fmaxf(m, logits[o]);
        float e[8], s = 0.0f;
        for (int o = 0; o < 8; ++o) { e[o] = expf(logits[o] - m); s += e[o]; }
        for (int o = 0; o < 8; ++o) out[OFF_PI + o] = e[o] / s;
        out[OFF_V] = logits[8];
    }
}

extern "C" void kernel_launch(void* const* d_in, const int* in_sizes, int n_in,
                              void* d_out, int out_size, void* d_ws, size_t ws_size,
                              hipStream_t stream)
{
    const float* x        = (const float*)d_in[0];
    const float* h        = (const float*)d_in[1];
    const float* c        = (const float*)d_in[2];
    const float* W_i2h    = (const float*)d_in[3];
    const float* b_i2h    = (const float*)d_in[4];
    const float* W_h2h    = (const float*)d_in[5];
    const float* b_h2h    = (const float*)d_in[6];
    const float* f_keys   = (const float*)d_in[7];
    const float* f_vals   = (const float*)d_in[8];
    const float* r_keys   = (const float*)d_in[9];
    const float* r_vals   = (const float*)d_in[10];
    const float* W_ih     = (const float*)d_in[11];
    const float* b_ih     = (const float*)d_in[12];
    const float* W_actor  = (const float*)d_in[13];
    const float* b_actor  = (const float*)d_in[14];
    const float* W_critic = (const float*)d_in[15];
    const float* b_critic = (const float*)d_in[16];
    const int*   widx     = (const int*)d_in[17];

    float* out = (float*)d_out;
    float* ws  = (float*)d_ws;

    // ws layout (floats)
    float* preact = ws;                 // 12288
    float* ef     = ws + 12288;         // 50000 (unnormalized exp sims, f)
    float* er     = ws + 62288;         // 50000 (unnormalized exp sims, r)
    float* memfun = ws + 112288;        // 2048 ┐
    float* memrul = ws + 114336;        // 2048 ├ zeroed together (4098 floats)
    float* sums   = ws + 116384;        // 2    ┘
    float* ht_ws  = ws + 116392;        // 2048 (16B-aligned)
    float* ha     = ws + 118440;        // 2048

    // 1. zero accumulators (ws is poisoned; atomics accumulate into these)
    k_zero<<<17, 256, 0, stream>>>(memfun, 2 * H + 2);

    // 2. LSTM preact GEMV (independent of 3/4; BW-bound, sequential is fine)
    k_preact<<<HD / 4, 256, 0, stream>>>(W_h2h, W_i2h, b_h2h, b_i2h, h, x, preact);

    // 3. grid-wide DND exp-sims + keys copies + sum reduction
    k_sims<<<dim3((DICT + 255) / 256, 2), 256, 0, stream>>>(
        f_keys, r_keys, x, ef, er, sums, out + OFF_FK, out + OFF_RK);

    // 4. fused vals copy + unnormalized weighted sums (dominant kernel)
    k_copy_wsum<<<dim3(DICT / ROWS_PER_CHUNK, 2, 2), 256, 0, stream>>>(
        f_vals, r_vals, ef, er, out + OFF_FV, out + OFF_RV, memfun, memrul);

    // 5. gates -> c_t, h_t (applies 1/sum normalization); h/c outputs + write_idx rows
    k_combine<<<H / 256, 256, 0, stream>>>(preact, c, memfun, memrul, sums, x, widx, out, ht_ws);

    // 6. heads
    k_hidden<<<H / 4, 256, 0, stream>>>(W_ih, b_ih, ht_ws, ha);
    k_heads<<<1, 256, 0, stream>>>(W_actor, b_actor, W_critic, b_critic, ha, out);
}

// Round 4
// 454.402 us; speedup vs baseline: 1.4649x; 1.0149x over previous
//
#include <hip/hip_runtime.h>
#include <math.h>

#define H        2048
#define HD       12288      // (NG+1)*H
#define DICT     50000
#define FDIM     6
#define RDIM     1
#define IN_DIM   16
#define EPS_F    1e-8f

// d_out flat offsets (floats), in reference return order
#define OFF_PI   ((size_t)0)
#define OFF_V    ((size_t)8)
#define OFF_H    ((size_t)9)
#define OFF_C    ((size_t)2057)
#define OFF_FK   ((size_t)4105)
#define OFF_FV   ((size_t)304105)
#define OFF_RK   ((size_t)102704105)
#define OFF_RV   ((size_t)102754105)

// megakernel block ranges
#define R_CHUNK      125                 // vals rows per block
#define NBLK_DICT    (DICT / R_CHUNK)    // 400
#define NBLK_VALS    (2 * NBLK_DICT)     // 800
#define NBLK_PREACT  (HD / 8)            // 1536 (8 rows per 512-thread block)
#define NBLK_TOTAL   (NBLK_VALS + NBLK_PREACT)

typedef float f4v __attribute__((ext_vector_type(4)));   // true vector type: NT-builtin-compatible

__device__ __forceinline__ float sigf(float v) { return 1.0f / (1.0f + expf(-v)); }

// ---------------- zero scratch accumulators ----------------
__global__ void k_zero(float* __restrict__ p, int n) {
    int i = blockIdx.x * 256 + threadIdx.x;
    if (i < n) p[i] = 0.0f;
}

// ---------------- megakernel: vals copy+wsum+sims (blocks 0..799) | preact (800..2335) ----
__global__ __launch_bounds__(512) void k_mega(
    const float* __restrict__ f_keys, const float* __restrict__ r_keys,
    const float* __restrict__ f_vals, const float* __restrict__ r_vals,
    const float* __restrict__ x,
    const float* __restrict__ W_h2h, const float* __restrict__ W_i2h,
    const float* __restrict__ b_h2h, const float* __restrict__ b_i2h,
    const float* __restrict__ h,
    float* __restrict__ out_fv, float* __restrict__ out_rv,
    float* __restrict__ out_fk, float* __restrict__ out_rk,
    float* __restrict__ memfun, float* __restrict__ memrul,
    float* __restrict__ sums, float* __restrict__ preact)
{
    const int b   = blockIdx.x;
    const int tid = threadIdx.x;

    if (b >= NBLK_VALS) {
        // ---- preact: wave per row, 8 rows per block ----
        const int row  = (b - NBLK_VALS) * 8 + (tid >> 6);
        const int lane = tid & 63;
        const float4* Wv = (const float4*)(W_h2h + (size_t)row * H);
        const float4* hv = (const float4*)h;
        float acc = 0.0f;
#pragma unroll
        for (int k = 0; k < 8; ++k) {
            float4 w4 = Wv[lane + (k << 6)];
            float4 h4 = hv[lane + (k << 6)];
            acc += w4.x * h4.x + w4.y * h4.y + w4.z * h4.z + w4.w * h4.w;
        }
        if (lane < IN_DIM) acc += W_i2h[(size_t)row * IN_DIM + lane] * x[lane];
#pragma unroll
        for (int off = 32; off > 0; off >>= 1) acc += __shfl_down(acc, off);
        if (lane == 0) preact[row] = acc + b_h2h[row] + b_i2h[row];
        return;
    }

    // ---- vals blocks: one full-width (512 float4) row per iteration ----
    __shared__ float wl[R_CHUNK];
    const int  dict = (b >= NBLK_DICT) ? 1 : 0;
    const int  row0 = (dict ? b - NBLK_DICT : b) * R_CHUNK;

    const float* vals = dict ? r_vals : f_vals;
    float*       outv = dict ? out_rv : out_fv;   // 4-byte-aligned base (odd float offset)
    float*       mem  = dict ? memrul : memfun;

    // fused keys output copy
    if (!dict) {
        for (int i = tid; i < R_CHUNK * FDIM; i += 512)
            out_fk[(size_t)row0 * FDIM + i] = f_keys[(size_t)row0 * FDIM + i];
    } else if (tid < R_CHUNK) {
        out_rk[row0 + tid] = r_keys[row0 + tid];
    }

    // fused exp-sims for this block's rows (softmax max-shift unneeded: |sim|<=1)
    if (tid < R_CHUNK) {
        const int row = row0 + tid;
        float e;
        if (!dict) {
            float qn[FDIM]; float qs = 0.0f;
#pragma unroll
            for (int d = 0; d < FDIM; ++d) { float q = x[d]; qn[d] = q; qs += q * q; }
            const float qi = 1.0f / (sqrtf(qs) + EPS_F);
            float ks = 0.0f, dot = 0.0f;
#pragma unroll
            for (int d = 0; d < FDIM; ++d) {
                float kv = f_keys[(size_t)row * FDIM + d];
                ks += kv * kv; dot += kv * qn[d];
            }
            e = expf((dot * qi) / (sqrtf(ks) + EPS_F));
        } else {
            float q  = x[FDIM];
            float kv = r_keys[row];
            e = expf((kv * (q / (fabsf(q) + EPS_F))) / (fabsf(kv) + EPS_F));
        }
        wl[tid] = e;
    }
    __syncthreads();
    if (tid == 0) {
        float s = 0.0f;
        for (int i = 0; i < R_CHUNK; ++i) s += wl[i];
        atomicAdd(&sums[dict], s);
    }

    // streaming copy + weighted sum; batch 5 rows: 5 NT loads -> FMAs -> 5 NT stores
    const f4v* vv = (const f4v*)vals;
    float a0 = 0.f, a1 = 0.f, a2 = 0.f, a3 = 0.f;
    size_t base = (size_t)row0 * 512 + tid;       // float4 index; thread owns column tid
    for (int i0 = 0; i0 < R_CHUNK; i0 += 5) {
        f4v v0 = __builtin_nontemporal_load(&vv[base]);
        f4v v1 = __builtin_nontemporal_load(&vv[base +  512]);
        f4v v2 = __builtin_nontemporal_load(&vv[base + 1024]);
        f4v v3 = __builtin_nontemporal_load(&vv[base + 1536]);
        f4v v4 = __builtin_nontemporal_load(&vv[base + 2048]);
        const float w0 = wl[i0], w1 = wl[i0+1], w2 = wl[i0+2], w3 = wl[i0+3], w4 = wl[i0+4];
        a0 += w0*v0.x + w1*v1.x + w2*v2.x + w3*v3.x + w4*v4.x;
        a1 += w0*v0.y + w1*v1.y + w2*v2.y + w3*v3.y + w4*v4.y;
        a2 += w0*v0.z + w1*v1.z + w2*v2.z + w3*v3.z + w4*v4.z;
        a3 += w0*v0.w + w1*v1.w + w2*v2.w + w3*v3.w + w4*v4.w;
        float* o0 = outv + (base        ) * 4;
        float* o1 = outv + (base +  512 ) * 4;
        float* o2 = outv + (base + 1024 ) * 4;
        float* o3 = outv + (base + 1536 ) * 4;
        float* o4 = outv + (base + 2048 ) * 4;
        __builtin_nontemporal_store(v0.x, o0+0); __builtin_nontemporal_store(v0.y, o0+1);
        __builtin_nontemporal_store(v0.z, o0+2); __builtin_nontemporal_store(v0.w, o0+3);
        __builtin_nontemporal_store(v1.x, o1+0); __builtin_nontemporal_store(v1.y, o1+1);
        __builtin_nontemporal_store(v1.z, o1+2); __builtin_nontemporal_store(v1.w, o1+3);
        __builtin_nontemporal_store(v2.x, o2+0); __builtin_nontemporal_store(v2.y, o2+1);
        __builtin_nontemporal_store(v2.z, o2+2); __builtin_nontemporal_store(v2.w, o2+3);
        __builtin_nontemporal_store(v3.x, o3+0); __builtin_nontemporal_store(v3.y, o3+1);
        __builtin_nontemporal_store(v3.z, o3+2); __builtin_nontemporal_store(v3.w, o3+3);
        __builtin_nontemporal_store(v4.x, o4+0); __builtin_nontemporal_store(v4.y, o4+1);
        __builtin_nontemporal_store(v4.z, o4+2); __builtin_nontemporal_store(v4.w, o4+3);
        base += 5 * 512;
    }
    const int c = tid * 4;
    atomicAdd(&mem[c + 0], a0);
    atomicAdd(&mem[c + 1], a1);
    atomicAdd(&mem[c + 2], a2);
    atomicAdd(&mem[c + 3], a3);
}

// ---------------- gates -> c_t, h_t; write h/c outputs + write_idx rows ----------------
__global__ __launch_bounds__(256) void k_combine(
    const float* __restrict__ preact, const float* __restrict__ c_in,
    const float* __restrict__ memfun, const float* __restrict__ memrul,
    const float* __restrict__ sums,
    const float* __restrict__ x, const int* __restrict__ widx_p,
    float* __restrict__ out, float* __restrict__ ht_ws)
{
    const int j = blockIdx.x * 256 + threadIdx.x;
    if (j >= H) return;
    const int widx = *widx_p;
    const float invf = 1.0f / sums[0];
    const float invr = 1.0f / sums[1];

    float f_t   = sigf(preact[0 * H + j]);
    float i_t   = sigf(preact[1 * H + j]);
    float o_t   = sigf(preact[2 * H + j]);
    float fun_t = sigf(preact[3 * H + j]);
    float rul_t = sigf(preact[4 * H + j]);
    float c_new = tanhf(preact[5 * H + j]);

    float ct = f_t * c_in[j] + i_t * c_new
             + fun_t * tanhf(memfun[j] * invf) + rul_t * tanhf(memrul[j] * invr);
    float ht = o_t * tanhf(ct);

    out[OFF_H + j] = ht;
    out[OFF_C + j] = ct;
    ht_ws[j] = ht;

    out[OFF_FV + (size_t)widx * H + j] = (j < H / 2) ? ct : 0.0f;
    out[OFF_RV + (size_t)widx * H + j] = (j < H / 2) ? 0.0f : ct;
    if (j < FDIM)  out[OFF_FK + (size_t)widx * FDIM + j] = x[j];
    if (j == FDIM) out[OFF_RK + (size_t)widx] = x[FDIM];
}

// ---------------- ha = relu(W_ih @ h_t + b_ih)  (wave per row) ----------------
__global__ __launch_bounds__(256) void k_hidden(
    const float* __restrict__ W_ih, const float* __restrict__ b_ih,
    const float* __restrict__ ht, float* __restrict__ ha)
{
    int gid  = blockIdx.x * blockDim.x + threadIdx.x;
    int row  = gid >> 6;
    int lane = threadIdx.x & 63;
    if (row >= H) return;
    const float4* Wv = (const float4*)(W_ih + (size_t)row * H);
    const float4* hv = (const float4*)ht;
    float acc = 0.0f;
#pragma unroll
    for (int k = 0; k < 8; ++k) {
        float4 w4 = Wv[lane + (k << 6)];
        float4 h4 = hv[lane + (k << 6)];
        acc += w4.x * h4.x + w4.y * h4.y + w4.z * h4.z + w4.w * h4.w;
    }
#pragma unroll
    for (int off = 32; off > 0; off >>= 1) acc += __shfl_down(acc, off);
    if (lane == 0) ha[row] = fmaxf(acc + b_ih[row], 0.0f);
}

// ---------------- actor softmax + critic ----------------
__global__ __launch_bounds__(256) void k_heads(
    const float* __restrict__ W_actor, const float* __restrict__ b_actor,
    const float* __restrict__ W_critic, const float* __restrict__ b_critic,
    const float* __restrict__ ha, float* __restrict__ out)
{
    __shared__ float red[4];
    __shared__ float logits[9];
    const int tid = threadIdx.x;

    for (int o = 0; o < 9; ++o) {
        const float* row = (o < 8) ? (W_actor + (size_t)o * H) : W_critic;
        float acc = 0.0f;
        for (int k = tid; k < H; k += 256) acc += row[k] * ha[k];
#pragma unroll
        for (int off = 32; off > 0; off >>= 1) acc += __shfl_down(acc, off);
        if ((tid & 63) == 0) red[tid >> 6] = acc;
        __syncthreads();
        if (tid == 0)
            logits[o] = red[0] + red[1] + red[2] + red[3] + ((o < 8) ? b_actor[o] : b_critic[0]);
        __syncthreads();
    }
    if (tid == 0) {
        float m = logits[0];
        for (int o = 1; o < 8; ++o) m = fmaxf(m, logits[o]);
        float e[8], s = 0.0f;
        for (int o = 0; o < 8; ++o) { e[o] = expf(logits[o] - m); s += e[o]; }
        for (int o = 0; o < 8; ++o) out[OFF_PI + o] = e[o] / s;
        out[OFF_V] = logits[8];
    }
}

extern "C" void kernel_launch(void* const* d_in, const int* in_sizes, int n_in,
                              void* d_out, int out_size, void* d_ws, size_t ws_size,
                              hipStream_t stream)
{
    const float* x        = (const float*)d_in[0];
    const float* h        = (const float*)d_in[1];
    const float* c        = (const float*)d_in[2];
    const float* W_i2h    = (const float*)d_in[3];
    const float* b_i2h    = (const float*)d_in[4];
    const float* W_h2h    = (const float*)d_in[5];
    const float* b_h2h    = (const float*)d_in[6];
    const float* f_keys   = (const float*)d_in[7];
    const float* f_vals   = (const float*)d_in[8];
    const float* r_keys   = (const float*)d_in[9];
    const float* r_vals   = (const float*)d_in[10];
    const float* W_ih     = (const float*)d_in[11];
    const float* b_ih     = (const float*)d_in[12];
    const float* W_actor  = (const float*)d_in[13];
    const float* b_actor  = (const float*)d_in[14];
    const float* W_critic = (const float*)d_in[15];
    const float* b_critic = (const float*)d_in[16];
    const int*   widx     = (const int*)d_in[17];

    float* out = (float*)d_out;
    float* ws  = (float*)d_ws;

    // ws layout (floats)
    float* preact = ws;                 // 12288
    float* memfun = ws + 12288;         // 2048 ┐
    float* memrul = ws + 14336;         // 2048 ├ zeroed together (4098 floats)
    float* sums   = ws + 16384;         // 2    ┘
    float* ht_ws  = ws + 16388;         // 2048 (16B-aligned: 16388*4 % 16 == 0)
    float* ha     = ws + 18436;         // 2048

    // 1. zero accumulators (ws is poisoned; atomics accumulate into these)
    k_zero<<<17, 256, 0, stream>>>(memfun, 2 * H + 2);

    // 2. megakernel: vals copy+wsum+sims+keys (blocks 0..799) | preact (800..2335)
    k_mega<<<NBLK_TOTAL, 512, 0, stream>>>(
        f_keys, r_keys, f_vals, r_vals, x,
        W_h2h, W_i2h, b_h2h, b_i2h, h,
        out + OFF_FV, out + OFF_RV, out + OFF_FK, out + OFF_RK,
        memfun, memrul, sums, preact);

    // 3. gates -> c_t, h_t (applies 1/sum normalization); h/c outputs + write_idx rows
    k_combine<<<H / 256, 256, 0, stream>>>(preact, c, memfun, memrul, sums, x, widx, out, ht_ws);

    // 4. heads
    k_hidden<<<H / 4, 256, 0, stream>>>(W_ih, b_ih, ht_ws, ha);
    k_heads<<<1, 256, 0, stream>>>(W_actor, b_actor, W_critic, b_critic, ha, out);
}